// Round 1
// baseline (3719.251 us; speedup 1.0000x reference)
//
#include <hip/hip_runtime.h>
#include <math.h>

// ---------------------------------------------------------------------------
// SelfIIWA block, fp32 baseline.
// Running activation X lives in d_out. Workspace holds: LN stats (mu,rsig),
// global-branch buffers, and a BIG slice buffer shared by window-QKV (per
// batch) and the MLP hidden (sliced by available ws).
// ---------------------------------------------------------------------------

#define DEV __device__ __forceinline__

constexpr int NTOK = 131072;     // 8*128*128
constexpr int TOKS_PER_B = 16384;
constexpr float SCALE_F = 0.17677669529663687f;  // 32^-0.5

DEV float gelu1(float v) { return 0.5f * v * (1.f + erff(v * 0.7071067811865476f)); }

// ---------------------------------------------------------------------------
// Generic fp32 GEMM: out[M][N] (+)= A'[M][K] @ W[N][K]^T + bias
//   A' = LNA ? (A-mu)*rsig*lnw+lnb (per-row stats) : A
//   GELU applied before residual-add. RES: out += (in-place safe when each
//   block covers all N columns of its own rows, i.e. gridDim.y==1).
// Tile: 64 rows x NT cols, K-chunk 32, transposed LDS [k][row].
// ---------------------------------------------------------------------------
template <int NT, bool LNA, bool RES, bool GELU>
__launch_bounds__(256)
__global__ void gemm_k(const float* A, const float* W, const float* __restrict__ bias,
                       float* out, const float* __restrict__ stats,
                       const float* __restrict__ lnw, const float* __restrict__ lnb,
                       int M, int N, int K) {
  constexpr int NC = NT / 64;                 // float4 col-groups per thread
  __shared__ float At[32][68];
  __shared__ float Wt[32][NT + 4];
  const int t = threadIdx.x;
  const int tx = t & 15, ty = t >> 4;
  const int m0 = blockIdx.x * 64, n0 = blockIdx.y * NT;

  float acc[4][NC * 4];
#pragma unroll
  for (int i = 0; i < 4; ++i)
#pragma unroll
    for (int j = 0; j < NC * 4; ++j) acc[i][j] = 0.f;

  const int ar = t >> 2;            // A row this thread stages (0..63)
  const int ak = (t & 3) * 8;       // k offset (0..24)
  float mu = 0.f, rs = 1.f;
  if (LNA) { mu = stats[(size_t)(m0 + ar) * 2]; rs = stats[(size_t)(m0 + ar) * 2 + 1]; }
  const float* Arow = A + (size_t)(m0 + ar) * K + ak;

  for (int k0 = 0; k0 < K; k0 += 32) {
    float4 a0 = *(const float4*)(Arow + k0);
    float4 a1 = *(const float4*)(Arow + k0 + 4);
    if (LNA) {
      float4 w0 = *(const float4*)(lnw + k0 + ak);
      float4 w1 = *(const float4*)(lnw + k0 + ak + 4);
      float4 b0 = *(const float4*)(lnb + k0 + ak);
      float4 b1 = *(const float4*)(lnb + k0 + ak + 4);
      a0.x = (a0.x - mu) * rs * w0.x + b0.x;  a0.y = (a0.y - mu) * rs * w0.y + b0.y;
      a0.z = (a0.z - mu) * rs * w0.z + b0.z;  a0.w = (a0.w - mu) * rs * w0.w + b0.w;
      a1.x = (a1.x - mu) * rs * w1.x + b1.x;  a1.y = (a1.y - mu) * rs * w1.y + b1.y;
      a1.z = (a1.z - mu) * rs * w1.z + b1.z;  a1.w = (a1.w - mu) * rs * w1.w + b1.w;
    }
    At[ak + 0][ar] = a0.x; At[ak + 1][ar] = a0.y; At[ak + 2][ar] = a0.z; At[ak + 3][ar] = a0.w;
    At[ak + 4][ar] = a1.x; At[ak + 5][ar] = a1.y; At[ak + 6][ar] = a1.z; At[ak + 7][ar] = a1.w;
#pragma unroll
    for (int it = 0; it < NT / 32; ++it) {
      const int rn = (t >> 3) + it * 32;
      const int kp = (t & 7) * 4;
      float4 w = *(const float4*)(W + (size_t)(n0 + rn) * K + k0 + kp);
      Wt[kp + 0][rn] = w.x; Wt[kp + 1][rn] = w.y; Wt[kp + 2][rn] = w.z; Wt[kp + 3][rn] = w.w;
    }
    __syncthreads();
#pragma unroll
    for (int kk = 0; kk < 32; ++kk) {
      float4 a = *(const float4*)&At[kk][ty * 4];
#pragma unroll
      for (int c = 0; c < NC; ++c) {
        float4 w = *(const float4*)&Wt[kk][c * 64 + tx * 4];
        acc[0][c*4+0] += a.x * w.x; acc[0][c*4+1] += a.x * w.y; acc[0][c*4+2] += a.x * w.z; acc[0][c*4+3] += a.x * w.w;
        acc[1][c*4+0] += a.y * w.x; acc[1][c*4+1] += a.y * w.y; acc[1][c*4+2] += a.y * w.z; acc[1][c*4+3] += a.y * w.w;
        acc[2][c*4+0] += a.z * w.x; acc[2][c*4+1] += a.z * w.y; acc[2][c*4+2] += a.z * w.z; acc[2][c*4+3] += a.z * w.w;
        acc[3][c*4+0] += a.w * w.x; acc[3][c*4+1] += a.w * w.y; acc[3][c*4+2] += a.w * w.z; acc[3][c*4+3] += a.w * w.w;
      }
    }
    __syncthreads();
  }
#pragma unroll
  for (int i = 0; i < 4; ++i) {
    const int m = m0 + ty * 4 + i;
#pragma unroll
    for (int c = 0; c < NC; ++c) {
      const int col = n0 + c * 64 + tx * 4;
      float4 b4 = *(const float4*)(bias + col);
      float4 r;
      r.x = acc[i][c*4+0] + b4.x; r.y = acc[i][c*4+1] + b4.y;
      r.z = acc[i][c*4+2] + b4.z; r.w = acc[i][c*4+3] + b4.w;
      if (GELU) { r.x = gelu1(r.x); r.y = gelu1(r.y); r.z = gelu1(r.z); r.w = gelu1(r.w); }
      float* op = out + (size_t)m * N + col;
      if (RES) {
        float4 o = *(const float4*)op;
        r.x += o.x; r.y += o.y; r.z += o.z; r.w += o.w;
      }
      *(float4*)op = r;
    }
  }
}

// ---------------------------------------------------------------------------
// Window attention: 1 wave per (window, head). qkv slice layout [tok][768].
// X[tok][h*32+j] = xin[...] + softmax(q k^T * scale + bias) v
// ---------------------------------------------------------------------------
__global__ void winattn_k(const float* __restrict__ qkv, const float* __restrict__ xin,
                          float* __restrict__ X, const float* __restrict__ rel_table,
                          const int* __restrict__ rel_idx, int b) {
  __shared__ float klds[64][36];
  __shared__ float vlds[64][36];
  const int widx = blockIdx.x >> 3, h = blockIdx.x & 7;
  const int wy = widx >> 4, wx = widx & 15;
  const int r = threadIdx.x;
  const int tl = (wy * 8 + (r >> 3)) * 128 + wx * 8 + (r & 7);
  const float* qr = qkv + (size_t)tl * 768 + h * 32;
  float q[32];
#pragma unroll
  for (int j4 = 0; j4 < 8; ++j4) {
    float4 v = *(const float4*)(qr + j4 * 4);
    q[j4*4+0] = v.x * SCALE_F; q[j4*4+1] = v.y * SCALE_F;
    q[j4*4+2] = v.z * SCALE_F; q[j4*4+3] = v.w * SCALE_F;
  }
#pragma unroll
  for (int j4 = 0; j4 < 8; ++j4) {
    *(float4*)&klds[r][j4 * 4] = *(const float4*)(qr + 256 + j4 * 4);
    *(float4*)&vlds[r][j4 * 4] = *(const float4*)(qr + 512 + j4 * 4);
  }
  __syncthreads();
  float s[64];
  const int* ri = rel_idx + r * 64;
#pragma unroll
  for (int m = 0; m < 64; ++m) {
    float acc = 0.f;
#pragma unroll
    for (int j4 = 0; j4 < 8; ++j4) {
      float4 k4 = *(const float4*)&klds[m][j4 * 4];
      acc += q[j4*4+0]*k4.x + q[j4*4+1]*k4.y + q[j4*4+2]*k4.z + q[j4*4+3]*k4.w;
    }
    s[m] = acc + rel_table[ri[m] * 8 + h];
  }
  float mx = s[0];
#pragma unroll
  for (int m = 1; m < 64; ++m) mx = fmaxf(mx, s[m]);
  float sum = 0.f;
#pragma unroll
  for (int m = 0; m < 64; ++m) { s[m] = __expf(s[m] - mx); sum += s[m]; }
  const float inv = 1.f / sum;
  float o[32];
#pragma unroll
  for (int j = 0; j < 32; ++j) o[j] = 0.f;
#pragma unroll
  for (int m = 0; m < 64; ++m) {
    const float p = s[m];
#pragma unroll
    for (int j4 = 0; j4 < 8; ++j4) {
      float4 v4 = *(const float4*)&vlds[m][j4 * 4];
      o[j4*4+0] += p * v4.x; o[j4*4+1] += p * v4.y;
      o[j4*4+2] += p * v4.z; o[j4*4+3] += p * v4.w;
    }
  }
  const size_t go = (size_t)(b * TOKS_PER_B + tl) * 256 + h * 32;
#pragma unroll
  for (int j4 = 0; j4 < 8; ++j4) {
    float4 xi = *(const float4*)(xin + go + j4 * 4);
    float4 rr;
    rr.x = o[j4*4+0] * inv + xi.x; rr.y = o[j4*4+1] * inv + xi.y;
    rr.z = o[j4*4+2] * inv + xi.z; rr.w = o[j4*4+3] * inv + xi.w;
    *(float4*)(X + go + j4 * 4) = rr;
  }
}

// ---------------------------------------------------------------------------
// Per-token LN stats (mu, 1/sqrt(var+eps)), one wave per token.
// ---------------------------------------------------------------------------
__global__ void lnstats_k(const float* __restrict__ X, float* __restrict__ stats) {
  const int lane = threadIdx.x & 63;
  const int wave = threadIdx.x >> 6;
  for (int tok = blockIdx.x * 4 + wave; tok < NTOK; tok += gridDim.x * 4) {
    float4 v = *(const float4*)(X + (size_t)tok * 256 + lane * 4);
    float s = v.x + v.y + v.z + v.w;
    float q = v.x*v.x + v.y*v.y + v.z*v.z + v.w*v.w;
#pragma unroll
    for (int off = 32; off > 0; off >>= 1) {
      s += __shfl_xor(s, off, 64);
      q += __shfl_xor(q, off, 64);
    }
    if (lane == 0) {
      const float m = s * (1.f / 256.f);
      const float var = q * (1.f / 256.f) - m * m;
      stats[(size_t)tok * 2] = m;
      stats[(size_t)tok * 2 + 1] = 1.f / sqrtf(var + 1e-5f);
    }
  }
}

// ---------------------------------------------------------------------------
// Final LN applied in place, one wave per token.
// ---------------------------------------------------------------------------
__global__ void finalln_k(float* X, const float* __restrict__ w, const float* __restrict__ b) {
  const int lane = threadIdx.x & 63;
  const int wave = threadIdx.x >> 6;
  for (int tok = blockIdx.x * 4 + wave; tok < NTOK; tok += gridDim.x * 4) {
    float* p = X + (size_t)tok * 256 + lane * 4;
    float4 v = *(const float4*)p;
    float s = v.x + v.y + v.z + v.w;
    float q = v.x*v.x + v.y*v.y + v.z*v.z + v.w*v.w;
#pragma unroll
    for (int off = 32; off > 0; off >>= 1) {
      s += __shfl_xor(s, off, 64);
      q += __shfl_xor(q, off, 64);
    }
    const float m = s * (1.f / 256.f);
    const float var = q * (1.f / 256.f) - m * m;
    const float rs = 1.f / sqrtf(var + 1e-5f);
    float4 w4 = *(const float4*)(w + lane * 4);
    float4 b4 = *(const float4*)(b + lane * 4);
    v.x = (v.x - m) * rs * w4.x + b4.x; v.y = (v.y - m) * rs * w4.y + b4.y;
    v.z = (v.z - m) * rs * w4.z + b4.z; v.w = (v.w - m) * rs * w4.w + b4.w;
    *(float4*)p = v;
  }
}

// ---------------------------------------------------------------------------
// Window avgpool + sine position encoding: G0[b,wy,wx,c]
// ---------------------------------------------------------------------------
__global__ void poolsine_k(const float* __restrict__ X, float* __restrict__ G0) {
  const int c = threadIdx.x;
  const int wx = blockIdx.x & 15, wy = (blockIdx.x >> 4) & 15, b = blockIdx.x >> 8;
  const float* base = X + ((size_t)(b * 128 + wy * 8) * 128 + wx * 8) * 256 + c;
  float s = 0.f;
  for (int ry = 0; ry < 8; ++ry)
#pragma unroll
    for (int rx = 0; rx < 8; ++rx) s += base[((size_t)ry * 128 + rx) * 256];
  s *= (1.f / 64.f);
  const float sc = 6.283185307179586f / (16.f + 1e-5f);
  const int cc = c & 127;
  const float d = powf(10000.f, (float)(cc >> 1) * (1.f / 64.f));
  const float e = ((c < 128 ? (float)(wy + 1) : (float)(wx + 1)) * sc) / d;
  const float pos = (cc & 1) ? cosf(e) : sinf(e);
  G0[(size_t)blockIdx.x * 256 + c] = s + pos;
}

// ---------------------------------------------------------------------------
// Global attention: block (b,h), thread = query row n (256). Online softmax.
// ---------------------------------------------------------------------------
__global__ void gattn_k(const float* __restrict__ G1, float* __restrict__ G2) {
  const int b = blockIdx.x, h = blockIdx.y, n = threadIdx.x;
  const float* qp = G1 + ((size_t)b * 256 + n) * 768 + h * 32;
  float q[32];
#pragma unroll
  for (int j4 = 0; j4 < 8; ++j4) {
    float4 v = *(const float4*)(qp + j4 * 4);
    q[j4*4+0] = v.x * SCALE_F; q[j4*4+1] = v.y * SCALE_F;
    q[j4*4+2] = v.z * SCALE_F; q[j4*4+3] = v.w * SCALE_F;
  }
  const float* kb = G1 + (size_t)b * 256 * 768 + 256 + h * 32;
  const float* vb = kb + 256;
  float out[32];
#pragma unroll
  for (int j = 0; j < 32; ++j) out[j] = 0.f;
  float mx = -3.4e38f, l = 0.f;
  for (int m = 0; m < 256; ++m) {
    const float* kr = kb + (size_t)m * 768;
    float s = 0.f;
#pragma unroll
    for (int j4 = 0; j4 < 8; ++j4) {
      float4 k4 = *(const float4*)(kr + j4 * 4);
      s += q[j4*4+0]*k4.x + q[j4*4+1]*k4.y + q[j4*4+2]*k4.z + q[j4*4+3]*k4.w;
    }
    const float mn = fmaxf(mx, s);
    const float corr = __expf(mx - mn);
    const float p = __expf(s - mn);
    l = l * corr + p;
    const float* vr = vb + (size_t)m * 768;
#pragma unroll
    for (int j4 = 0; j4 < 8; ++j4) {
      float4 v4 = *(const float4*)(vr + j4 * 4);
      out[j4*4+0] = out[j4*4+0]*corr + p*v4.x; out[j4*4+1] = out[j4*4+1]*corr + p*v4.y;
      out[j4*4+2] = out[j4*4+2]*corr + p*v4.z; out[j4*4+3] = out[j4*4+3]*corr + p*v4.w;
    }
    mx = mn;
  }
  const float inv = 1.f / l;
  float* op = G2 + ((size_t)b * 256 + n) * 256 + h * 32;
#pragma unroll
  for (int j4 = 0; j4 < 8; ++j4) {
    float4 r;
    r.x = out[j4*4+0]*inv; r.y = out[j4*4+1]*inv;
    r.z = out[j4*4+2]*inv; r.w = out[j4*4+3]*inv;
    *(float4*)(op + j4 * 4) = r;
  }
}

// ---------------------------------------------------------------------------
// Bilinear upsample (align_corners) of G2 (b,16,16,256) added into X; also
// emits the LN stats of the updated token (for proj2_ln).
// ---------------------------------------------------------------------------
__global__ void upadd_k(float* __restrict__ X, const float* __restrict__ G2,
                        float* __restrict__ stats) {
  const int c = threadIdx.x;
  const int tok = blockIdx.x;
  const int j = tok & 127, i = (tok >> 7) & 127, b = tok >> 14;
  const float sy = i * (15.f / 127.f);
  const float sx = j * (15.f / 127.f);
  const int y0 = (int)sy; const float ty = sy - y0; const int y1 = min(y0 + 1, 15);
  const int x0 = (int)sx; const float tx = sx - x0; const int x1 = min(x0 + 1, 15);
  const float* gb = G2 + (size_t)b * 256 * 256;
  const float v00 = gb[((size_t)(y0 * 16 + x0)) * 256 + c];
  const float v01 = gb[((size_t)(y0 * 16 + x1)) * 256 + c];
  const float v10 = gb[((size_t)(y1 * 16 + x0)) * 256 + c];
  const float v11 = gb[((size_t)(y1 * 16 + x1)) * 256 + c];
  const float vy0 = v00 * (1.f - ty) + v10 * ty;
  const float vy1 = v01 * (1.f - ty) + v11 * ty;
  const float val = X[(size_t)tok * 256 + c] + vy0 * (1.f - tx) + vy1 * tx;
  X[(size_t)tok * 256 + c] = val;
  float s = val, q = val * val;
#pragma unroll
  for (int off = 32; off > 0; off >>= 1) {
    s += __shfl_xor(s, off, 64);
    q += __shfl_xor(q, off, 64);
  }
  __shared__ float red[8];
  const int lane = c & 63, wave = c >> 6;
  if (lane == 0) { red[wave * 2] = s; red[wave * 2 + 1] = q; }
  __syncthreads();
  if (c == 0) {
    const float S = red[0] + red[2] + red[4] + red[6];
    const float Q = red[1] + red[3] + red[5] + red[7];
    const float m = S * (1.f / 256.f);
    const float var = Q * (1.f / 256.f) - m * m;
    stats[(size_t)tok * 2] = m;
    stats[(size_t)tok * 2 + 1] = 1.f / sqrtf(var + 1e-5f);
  }
}

// ---------------------------------------------------------------------------
extern "C" void kernel_launch(void* const* d_in, const int* in_sizes, int n_in,
                              void* d_out, int out_size, void* d_ws, size_t ws_size,
                              hipStream_t stream) {
  const float* x          = (const float*)d_in[0];
  const float* rel_table  = (const float*)d_in[1];
  const float* qkv_w      = (const float*)d_in[2];
  const float* qkv_b      = (const float*)d_in[3];
  const float* qkv2_w     = (const float*)d_in[4];
  const float* qkv2_b     = (const float*)d_in[5];
  const float* proj_ln_w  = (const float*)d_in[6];
  const float* proj_ln_b  = (const float*)d_in[7];
  const float* proj_w     = (const float*)d_in[8];
  const float* proj_b     = (const float*)d_in[9];
  const float* proj2_ln_w = (const float*)d_in[10];
  const float* proj2_ln_b = (const float*)d_in[11];
  const float* proj2_w    = (const float*)d_in[12];
  const float* proj2_b    = (const float*)d_in[13];
  const float* norm1_w    = (const float*)d_in[14];
  const float* norm1_b    = (const float*)d_in[15];
  const float* norm2_w    = (const float*)d_in[16];
  const float* norm2_b    = (const float*)d_in[17];
  const float* fc1_w      = (const float*)d_in[18];
  const float* fc1_b      = (const float*)d_in[19];
  const float* fc2_w      = (const float*)d_in[20];
  const float* fc2_b      = (const float*)d_in[21];
  const int*   rel_idx    = (const int*)d_in[22];

  float* X = (float*)d_out;
  char* wsb = (char*)d_ws;
  float* stats = (float*)wsb;                       // NTOK*2
  float* G0 = (float*)(wsb + (size_t)NTOK * 2 * 4); // 2048*256
  float* G1 = G0 + (size_t)2048 * 256;              // 2048*768
  float* G2 = G1 + (size_t)2048 * 768;              // 2048*256
  float* BIG = G2 + (size_t)2048 * 256;             // qkv slice / mlp hidden
  const size_t used = (size_t)((char*)BIG - wsb);
  const size_t avail = ws_size > used ? ws_size - used : 0;
  int st = 8192;  // MLP token-slice size
  if (avail >= (size_t)65536 * 1024 * 4) st = 65536;
  else if (avail >= (size_t)32768 * 1024 * 4) st = 32768;
  else if (avail >= (size_t)16384 * 1024 * 4) st = 16384;

  // ---- window branch: qkv GEMM + attention per batch ----
  for (int b = 0; b < 8; ++b) {
    gemm_k<256, false, false, false><<<dim3(TOKS_PER_B / 64, 3), 256, 0, stream>>>(
        x + (size_t)b * TOKS_PER_B * 256, qkv_w, qkv_b, BIG,
        nullptr, nullptr, nullptr, TOKS_PER_B, 768, 256);
    winattn_k<<<dim3(2048), 64, 0, stream>>>(BIG, x, X, rel_table, rel_idx, b);
  }
  // ---- proj (x += LN(x) @ W^T + b) ----
  lnstats_k<<<1024, 256, 0, stream>>>(X, stats);
  gemm_k<256, true, true, false><<<dim3(NTOK / 64, 1), 256, 0, stream>>>(
      X, proj_w, proj_b, X, stats, proj_ln_w, proj_ln_b, NTOK, 256, 256);
  // ---- global branch ----
  poolsine_k<<<2048, 256, 0, stream>>>(X, G0);
  gemm_k<64, false, false, false><<<dim3(32, 12), 256, 0, stream>>>(
      G0, qkv2_w, qkv2_b, G1, nullptr, nullptr, nullptr, 2048, 768, 256);
  gattn_k<<<dim3(8, 8), 256, 0, stream>>>(G1, G2);
  upadd_k<<<NTOK, 256, 0, stream>>>(X, G2, stats);  // also emits proj2_ln stats
  gemm_k<256, true, true, false><<<dim3(NTOK / 64, 1), 256, 0, stream>>>(
      X, proj2_w, proj2_b, X, stats, proj2_ln_w, proj2_ln_b, NTOK, 256, 256);
  // ---- MLP ----
  lnstats_k<<<1024, 256, 0, stream>>>(X, stats);
  for (int s0 = 0; s0 < NTOK; s0 += st) {
    gemm_k<256, true, false, true><<<dim3(st / 64, 4), 256, 0, stream>>>(
        X + (size_t)s0 * 256, fc1_w, fc1_b, BIG, stats + (size_t)s0 * 2,
        norm1_w, norm1_b, st, 1024, 256);
    gemm_k<256, false, true, false><<<dim3(st / 64, 1), 256, 0, stream>>>(
        BIG, fc2_w, fc2_b, X + (size_t)s0 * 256, nullptr, nullptr, nullptr,
        st, 256, 1024);
  }
  // ---- final LN ----
  finalln_k<<<1024, 256, 0, stream>>>(X, norm2_w, norm2_b);
}

// Round 3
// 2129.172 us; speedup vs baseline: 1.7468x; 1.7468x over previous
//
#include <hip/hip_runtime.h>
#include <math.h>

#define DEV __device__ __forceinline__

constexpr int NTOK = 131072;     // 8*128*128
constexpr int TOKS_PER_B = 16384;
constexpr float SCALE_F = 0.17677669529663687f;  // 32^-0.5

typedef float f32x4 __attribute__((ext_vector_type(4)));
typedef __bf16 bf16x8 __attribute__((ext_vector_type(8)));
typedef unsigned short us8 __attribute__((ext_vector_type(8)));

DEV float gelu1(float v) { return 0.5f * v * (1.f + erff(v * 0.7071067811865476f)); }
DEV unsigned short f2bf(float x) { __bf16 b = (__bf16)x; return __builtin_bit_cast(unsigned short, b); }
DEV float bfh2f(unsigned short h) { return __builtin_bit_cast(float, ((unsigned)h) << 16); }

// ---------------------------------------------------------------------------
// Weight pre-split: fp32 -> bf16 hi plane + bf16 lo plane (n elements each).
// ---------------------------------------------------------------------------
__global__ void cvtw_k(const float* __restrict__ w, unsigned short* __restrict__ dst, int n) {
  const int i = (blockIdx.x * 256 + threadIdx.x) * 4;
  float4 v = *(const float4*)(w + i);
  ushort4 h, l;
  h.x = f2bf(v.x); l.x = f2bf(v.x - bfh2f(h.x));
  h.y = f2bf(v.y); l.y = f2bf(v.y - bfh2f(h.y));
  h.z = f2bf(v.z); l.z = f2bf(v.z - bfh2f(h.z));
  h.w = f2bf(v.w); l.w = f2bf(v.w - bfh2f(h.w));
  *(ushort4*)(dst + i) = h;
  *(ushort4*)(dst + n + i) = l;
}

// ---------------------------------------------------------------------------
// Split-bf16 MFMA GEMM: out[M][N] (+)= A'[M][K] @ W[N][K]^T + bias
//   A' = LNA ? (A-mu)*rsig*lnw+lnb : A   (fp32, split hi/lo in staging)
//   W pre-split into hi/lo planes. acc += Ah*Wh + Ah*Wl + Al*Wh (fp32 acc).
// Tile 64(M) x 256(N), 4 waves (each 64x64), K-chunk 32.
// LDS rows padded to 40 bf16 (80 B = 20 banks -> ~2-way, free).
// In-place residual safe when gridDim.y==1 (block owns full rows).
// ---------------------------------------------------------------------------
template <bool LNA, bool RES, bool GELU>
__launch_bounds__(256)
__global__ void gemm_mfma(const float* __restrict__ A, const unsigned short* __restrict__ Wp,
                          const float* __restrict__ bias, float* out,
                          const float* __restrict__ stats,
                          const float* __restrict__ lnw, const float* __restrict__ lnb,
                          int M, int N, int K) {
  __shared__ unsigned short Ah[64][40], Al[64][40];
  __shared__ unsigned short Wh[256][40], Wl[256][40];
  const int t = threadIdx.x;
  const int lane = t & 63, wid = t >> 6;     // wid: n-block 0..3 (64 cols each)
  const int m0 = blockIdx.x * 64, n0 = blockIdx.y * 256;
  const unsigned short* Whp = Wp;
  const unsigned short* Wlp = Wp + (size_t)N * K;

  f32x4 acc[4][4];
#pragma unroll
  for (int i = 0; i < 4; ++i)
#pragma unroll
    for (int j = 0; j < 4; ++j) acc[i][j] = (f32x4){0.f, 0.f, 0.f, 0.f};

  const int fr = lane & 15, ko = (lane >> 4) * 8;

  for (int k0 = 0; k0 < K; k0 += 32) {
    // ---- stage A (64x32 fp32 -> hi/lo bf16), 2 iters x 256 threads ----
#pragma unroll
    for (int it = 0; it < 2; ++it) {
      const int id = t + it * 256;
      const int r = id >> 3, cg = id & 7;
      float4 v = *(const float4*)(A + (size_t)(m0 + r) * K + k0 + cg * 4);
      if (LNA) {
        const float mu = stats[(size_t)(m0 + r) * 2];
        const float rs = stats[(size_t)(m0 + r) * 2 + 1];
        float4 w4 = *(const float4*)(lnw + k0 + cg * 4);
        float4 b4 = *(const float4*)(lnb + k0 + cg * 4);
        v.x = (v.x - mu) * rs * w4.x + b4.x; v.y = (v.y - mu) * rs * w4.y + b4.y;
        v.z = (v.z - mu) * rs * w4.z + b4.z; v.w = (v.w - mu) * rs * w4.w + b4.w;
      }
      ushort4 h, l;
      h.x = f2bf(v.x); l.x = f2bf(v.x - bfh2f(h.x));
      h.y = f2bf(v.y); l.y = f2bf(v.y - bfh2f(h.y));
      h.z = f2bf(v.z); l.z = f2bf(v.z - bfh2f(h.z));
      h.w = f2bf(v.w); l.w = f2bf(v.w - bfh2f(h.w));
      *(ushort4*)&Ah[r][cg * 4] = h;
      *(ushort4*)&Al[r][cg * 4] = l;
    }
    // ---- stage W (256x32 bf16 hi/lo), 4 iters each plane ----
#pragma unroll
    for (int it = 0; it < 4; ++it) {
      const int id = t + it * 256;
      const int rn = id >> 2, kc = (id & 3) * 8;
      const size_t goff = (size_t)(n0 + rn) * K + k0 + kc;
      *(us8*)&Wh[rn][kc] = *(const us8*)(Whp + goff);
      *(us8*)&Wl[rn][kc] = *(const us8*)(Wlp + goff);
    }
    __syncthreads();
    // ---- fragments + MFMA ----
    bf16x8 ah[4], al[4], bh[4], bl[4];
#pragma unroll
    for (int i = 0; i < 4; ++i) {
      ah[i] = __builtin_bit_cast(bf16x8, *(const us8*)&Ah[i * 16 + fr][ko]);
      al[i] = __builtin_bit_cast(bf16x8, *(const us8*)&Al[i * 16 + fr][ko]);
      bh[i] = __builtin_bit_cast(bf16x8, *(const us8*)&Wh[wid * 64 + i * 16 + fr][ko]);
      bl[i] = __builtin_bit_cast(bf16x8, *(const us8*)&Wl[wid * 64 + i * 16 + fr][ko]);
    }
#pragma unroll
    for (int i = 0; i < 4; ++i)
#pragma unroll
      for (int j = 0; j < 4; ++j) {
        acc[i][j] = __builtin_amdgcn_mfma_f32_16x16x32_bf16(ah[i], bh[j], acc[i][j], 0, 0, 0);
        acc[i][j] = __builtin_amdgcn_mfma_f32_16x16x32_bf16(ah[i], bl[j], acc[i][j], 0, 0, 0);
        acc[i][j] = __builtin_amdgcn_mfma_f32_16x16x32_bf16(al[i], bh[j], acc[i][j], 0, 0, 0);
      }
    __syncthreads();
  }
  // ---- epilogue: C row = m0 + i*16 + (lane>>4)*4 + r, col = n0+wid*64+j*16+fr
  const int orow = (lane >> 4) * 4;
#pragma unroll
  for (int i = 0; i < 4; ++i)
#pragma unroll
    for (int j = 0; j < 4; ++j) {
      const int col = n0 + wid * 64 + j * 16 + fr;
      const float b = bias[col];
#pragma unroll
      for (int r = 0; r < 4; ++r) {
        const int row = m0 + i * 16 + orow + r;
        float v = acc[i][j][r] + b;
        if (GELU) v = gelu1(v);
        float* p = out + (size_t)row * N + col;
        if (RES) v += *p;
        *p = v;
      }
    }
}

// ---------------------------------------------------------------------------
// Window attention: 1 wave per (batch_rel, window, head). qkv layout [tok][768].
// ---------------------------------------------------------------------------
__global__ void winattn_k(const float* __restrict__ qkv, const float* __restrict__ xin,
                          float* __restrict__ X, const float* __restrict__ rel_table,
                          const int* __restrict__ rel_idx, int b0) {
  __shared__ float klds[64][36];
  __shared__ float vlds[64][36];
  const int b_rel = blockIdx.x >> 11;
  const int rest = blockIdx.x & 2047;
  const int widx = rest >> 3, h = rest & 7;
  const int wy = widx >> 4, wx = widx & 15;
  const int r = threadIdx.x;
  const int tl = (wy * 8 + (r >> 3)) * 128 + wx * 8 + (r & 7);
  const float* qr = qkv + ((size_t)b_rel * TOKS_PER_B + tl) * 768 + h * 32;
  float q[32];
#pragma unroll
  for (int j4 = 0; j4 < 8; ++j4) {
    float4 v = *(const float4*)(qr + j4 * 4);
    q[j4*4+0] = v.x * SCALE_F; q[j4*4+1] = v.y * SCALE_F;
    q[j4*4+2] = v.z * SCALE_F; q[j4*4+3] = v.w * SCALE_F;
  }
#pragma unroll
  for (int j4 = 0; j4 < 8; ++j4) {
    *(float4*)&klds[r][j4 * 4] = *(const float4*)(qr + 256 + j4 * 4);
    *(float4*)&vlds[r][j4 * 4] = *(const float4*)(qr + 512 + j4 * 4);
  }
  __syncthreads();
  float s[64];
  const int* ri = rel_idx + r * 64;
#pragma unroll
  for (int m = 0; m < 64; ++m) {
    float acc = 0.f;
#pragma unroll
    for (int j4 = 0; j4 < 8; ++j4) {
      float4 k4 = *(const float4*)&klds[m][j4 * 4];
      acc += q[j4*4+0]*k4.x + q[j4*4+1]*k4.y + q[j4*4+2]*k4.z + q[j4*4+3]*k4.w;
    }
    s[m] = acc + rel_table[ri[m] * 8 + h];
  }
  float mx = s[0];
#pragma unroll
  for (int m = 1; m < 64; ++m) mx = fmaxf(mx, s[m]);
  float sum = 0.f;
#pragma unroll
  for (int m = 0; m < 64; ++m) { s[m] = __expf(s[m] - mx); sum += s[m]; }
  const float inv = 1.f / sum;
  float o[32];
#pragma unroll
  for (int j = 0; j < 32; ++j) o[j] = 0.f;
#pragma unroll
  for (int m = 0; m < 64; ++m) {
    const float p = s[m];
#pragma unroll
    for (int j4 = 0; j4 < 8; ++j4) {
      float4 v4 = *(const float4*)&vlds[m][j4 * 4];
      o[j4*4+0] += p * v4.x; o[j4*4+1] += p * v4.y;
      o[j4*4+2] += p * v4.z; o[j4*4+3] += p * v4.w;
    }
  }
  const size_t go = (size_t)((b0 + b_rel) * TOKS_PER_B + tl) * 256 + h * 32;
#pragma unroll
  for (int j4 = 0; j4 < 8; ++j4) {
    float4 xi = *(const float4*)(xin + go + j4 * 4);
    float4 rr;
    rr.x = o[j4*4+0] * inv + xi.x; rr.y = o[j4*4+1] * inv + xi.y;
    rr.z = o[j4*4+2] * inv + xi.z; rr.w = o[j4*4+3] * inv + xi.w;
    *(float4*)(X + go + j4 * 4) = rr;
  }
}

// ---------------------------------------------------------------------------
__global__ void lnstats_k(const float* __restrict__ X, float* __restrict__ stats) {
  const int lane = threadIdx.x & 63;
  const int wave = threadIdx.x >> 6;
  for (int tok = blockIdx.x * 4 + wave; tok < NTOK; tok += gridDim.x * 4) {
    float4 v = *(const float4*)(X + (size_t)tok * 256 + lane * 4);
    float s = v.x + v.y + v.z + v.w;
    float q = v.x*v.x + v.y*v.y + v.z*v.z + v.w*v.w;
#pragma unroll
    for (int off = 32; off > 0; off >>= 1) {
      s += __shfl_xor(s, off, 64);
      q += __shfl_xor(q, off, 64);
    }
    if (lane == 0) {
      const float m = s * (1.f / 256.f);
      const float var = q * (1.f / 256.f) - m * m;
      stats[(size_t)tok * 2] = m;
      stats[(size_t)tok * 2 + 1] = 1.f / sqrtf(var + 1e-5f);
    }
  }
}

__global__ void finalln_k(float* X, const float* __restrict__ w, const float* __restrict__ b) {
  const int lane = threadIdx.x & 63;
  const int wave = threadIdx.x >> 6;
  for (int tok = blockIdx.x * 4 + wave; tok < NTOK; tok += gridDim.x * 4) {
    float* p = X + (size_t)tok * 256 + lane * 4;
    float4 v = *(const float4*)p;
    float s = v.x + v.y + v.z + v.w;
    float q = v.x*v.x + v.y*v.y + v.z*v.z + v.w*v.w;
#pragma unroll
    for (int off = 32; off > 0; off >>= 1) {
      s += __shfl_xor(s, off, 64);
      q += __shfl_xor(q, off, 64);
    }
    const float m = s * (1.f / 256.f);
    const float var = q * (1.f / 256.f) - m * m;
    const float rs = 1.f / sqrtf(var + 1e-5f);
    float4 w4 = *(const float4*)(w + lane * 4);
    float4 b4 = *(const float4*)(b + lane * 4);
    v.x = (v.x - m) * rs * w4.x + b4.x; v.y = (v.y - m) * rs * w4.y + b4.y;
    v.z = (v.z - m) * rs * w4.z + b4.z; v.w = (v.w - m) * rs * w4.w + b4.w;
    *(float4*)p = v;
  }
}

__global__ void poolsine_k(const float* __restrict__ X, float* __restrict__ G0) {
  const int c = threadIdx.x;
  const int wx = blockIdx.x & 15, wy = (blockIdx.x >> 4) & 15, b = blockIdx.x >> 8;
  const float* base = X + ((size_t)(b * 128 + wy * 8) * 128 + wx * 8) * 256 + c;
  float s = 0.f;
  for (int ry = 0; ry < 8; ++ry)
#pragma unroll
    for (int rx = 0; rx < 8; ++rx) s += base[((size_t)ry * 128 + rx) * 256];
  s *= (1.f / 64.f);
  const float sc = 6.283185307179586f / (16.f + 1e-5f);
  const int cc = c & 127;
  const float d = powf(10000.f, (float)(cc >> 1) * (1.f / 64.f));
  const float e = ((c < 128 ? (float)(wy + 1) : (float)(wx + 1)) * sc) / d;
  const float pos = (cc & 1) ? cosf(e) : sinf(e);
  G0[(size_t)blockIdx.x * 256 + c] = s + pos;
}

__global__ void gattn_k(const float* __restrict__ G1, float* __restrict__ G2) {
  const int b = blockIdx.x, h = blockIdx.y, n = threadIdx.x;
  const float* qp = G1 + ((size_t)b * 256 + n) * 768 + h * 32;
  float q[32];
#pragma unroll
  for (int j4 = 0; j4 < 8; ++j4) {
    float4 v = *(const float4*)(qp + j4 * 4);
    q[j4*4+0] = v.x * SCALE_F; q[j4*4+1] = v.y * SCALE_F;
    q[j4*4+2] = v.z * SCALE_F; q[j4*4+3] = v.w * SCALE_F;
  }
  const float* kb = G1 + (size_t)b * 256 * 768 + 256 + h * 32;
  const float* vb = kb + 256;
  float out[32];
#pragma unroll
  for (int j = 0; j < 32; ++j) out[j] = 0.f;
  float mx = -3.4e38f, l = 0.f;
  for (int m = 0; m < 256; ++m) {
    const float* kr = kb + (size_t)m * 768;
    float s = 0.f;
#pragma unroll
    for (int j4 = 0; j4 < 8; ++j4) {
      float4 k4 = *(const float4*)(kr + j4 * 4);
      s += q[j4*4+0]*k4.x + q[j4*4+1]*k4.y + q[j4*4+2]*k4.z + q[j4*4+3]*k4.w;
    }
    const float mn = fmaxf(mx, s);
    const float corr = __expf(mx - mn);
    const float p = __expf(s - mn);
    l = l * corr + p;
    const float* vr = vb + (size_t)m * 768;
#pragma unroll
    for (int j4 = 0; j4 < 8; ++j4) {
      float4 v4 = *(const float4*)(vr + j4 * 4);
      out[j4*4+0] = out[j4*4+0]*corr + p*v4.x; out[j4*4+1] = out[j4*4+1]*corr + p*v4.y;
      out[j4*4+2] = out[j4*4+2]*corr + p*v4.z; out[j4*4+3] = out[j4*4+3]*corr + p*v4.w;
    }
    mx = mn;
  }
  const float inv = 1.f / l;
  float* op = G2 + ((size_t)b * 256 + n) * 256 + h * 32;
#pragma unroll
  for (int j4 = 0; j4 < 8; ++j4) {
    float4 r;
    r.x = out[j4*4+0]*inv; r.y = out[j4*4+1]*inv;
    r.z = out[j4*4+2]*inv; r.w = out[j4*4+3]*inv;
    *(float4*)(op + j4 * 4) = r;
  }
}

__global__ void upadd_k(float* __restrict__ X, const float* __restrict__ G2,
                        float* __restrict__ stats) {
  const int c = threadIdx.x;
  const int tok = blockIdx.x;
  const int j = tok & 127, i = (tok >> 7) & 127, b = tok >> 14;
  const float sy = i * (15.f / 127.f);
  const float sx = j * (15.f / 127.f);
  const int y0 = (int)sy; const float ty = sy - y0; const int y1 = min(y0 + 1, 15);
  const int x0 = (int)sx; const float tx = sx - x0; const int x1 = min(x0 + 1, 15);
  const float* gb = G2 + (size_t)b * 256 * 256;
  const float v00 = gb[((size_t)(y0 * 16 + x0)) * 256 + c];
  const float v01 = gb[((size_t)(y0 * 16 + x1)) * 256 + c];
  const float v10 = gb[((size_t)(y1 * 16 + x0)) * 256 + c];
  const float v11 = gb[((size_t)(y1 * 16 + x1)) * 256 + c];
  const float vy0 = v00 * (1.f - ty) + v10 * ty;
  const float vy1 = v01 * (1.f - ty) + v11 * ty;
  const float val = X[(size_t)tok * 256 + c] + vy0 * (1.f - tx) + vy1 * tx;
  X[(size_t)tok * 256 + c] = val;
  float s = val, q = val * val;
#pragma unroll
  for (int off = 32; off > 0; off >>= 1) {
    s += __shfl_xor(s, off, 64);
    q += __shfl_xor(q, off, 64);
  }
  __shared__ float red[8];
  const int lane = c & 63, wave = c >> 6;
  if (lane == 0) { red[wave * 2] = s; red[wave * 2 + 1] = q; }
  __syncthreads();
  if (c == 0) {
    const float S = red[0] + red[2] + red[4] + red[6];
    const float Q = red[1] + red[3] + red[5] + red[7];
    const float m = S * (1.f / 256.f);
    const float var = Q * (1.f / 256.f) - m * m;
    stats[(size_t)tok * 2] = m;
    stats[(size_t)tok * 2 + 1] = 1.f / sqrtf(var + 1e-5f);
  }
}

// ---------------------------------------------------------------------------
extern "C" void kernel_launch(void* const* d_in, const int* in_sizes, int n_in,
                              void* d_out, int out_size, void* d_ws, size_t ws_size,
                              hipStream_t stream) {
  const float* x          = (const float*)d_in[0];
  const float* rel_table  = (const float*)d_in[1];
  const float* qkv_w      = (const float*)d_in[2];
  const float* qkv_b      = (const float*)d_in[3];
  const float* qkv2_w     = (const float*)d_in[4];
  const float* qkv2_b     = (const float*)d_in[5];
  const float* proj_ln_w  = (const float*)d_in[6];
  const float* proj_ln_b  = (const float*)d_in[7];
  const float* proj_w     = (const float*)d_in[8];
  const float* proj_b     = (const float*)d_in[9];
  const float* proj2_ln_w = (const float*)d_in[10];
  const float* proj2_ln_b = (const float*)d_in[11];
  const float* proj2_w    = (const float*)d_in[12];
  const float* proj2_b    = (const float*)d_in[13];
  const float* norm1_w    = (const float*)d_in[14];
  const float* norm1_b    = (const float*)d_in[15];
  const float* norm2_w    = (const float*)d_in[16];
  const float* norm2_b    = (const float*)d_in[17];
  const float* fc1_w      = (const float*)d_in[18];
  const float* fc1_b      = (const float*)d_in[19];
  const float* fc2_w      = (const float*)d_in[20];
  const float* fc2_b      = (const float*)d_in[21];
  const int*   rel_idx    = (const int*)d_in[22];

  float* X = (float*)d_out;
  char* wsb = (char*)d_ws;
  float* stats = (float*)wsb;                               // 1 MB
  float* G0 = (float*)(wsb + (size_t)1048576);              // 2 MB
  float* G1 = G0 + (size_t)2048 * 256;                      // 6 MB
  float* G2 = G1 + (size_t)2048 * 768;                      // 2 MB
  unsigned short* WCVT = (unsigned short*)(G2 + (size_t)2048 * 256);  // 4 MB
  float* BIG = (float*)((char*)WCVT + (size_t)4194304);
  const size_t fixed = (size_t)((char*)BIG - wsb);
  const size_t avail = ws_size > fixed ? ws_size - fixed : 0;

  // weight split offsets (ushort units)
  unsigned short* w_qkv  = WCVT;
  unsigned short* w_qkv2 = WCVT + 393216;
  unsigned short* w_proj = WCVT + 786432;
  unsigned short* w_proj2= WCVT + 917504;
  unsigned short* w_fc1  = WCVT + 1048576;
  unsigned short* w_fc2  = WCVT + 1572864;
  cvtw_k<<<192, 256, 0, stream>>>(qkv_w,   w_qkv,   196608);
  cvtw_k<<<192, 256, 0, stream>>>(qkv2_w,  w_qkv2,  196608);
  cvtw_k<<<64,  256, 0, stream>>>(proj_w,  w_proj,   65536);
  cvtw_k<<<64,  256, 0, stream>>>(proj2_w, w_proj2,  65536);
  cvtw_k<<<256, 256, 0, stream>>>(fc1_w,   w_fc1,   262144);
  cvtw_k<<<256, 256, 0, stream>>>(fc2_w,   w_fc2,   262144);

  int st = 8192;  // MLP token-slice
  if (avail >= (size_t)65536 * 1024 * 4) st = 65536;
  else if (avail >= (size_t)32768 * 1024 * 4) st = 32768;
  else if (avail >= (size_t)16384 * 1024 * 4) st = 16384;
  const bool one_shot_qkv = avail >= (size_t)NTOK * 768 * 4;

  // ---- window branch ----
  if (one_shot_qkv) {
    gemm_mfma<false, false, false><<<dim3(NTOK / 64, 3), 256, 0, stream>>>(
        x, w_qkv, qkv_b, BIG, nullptr, nullptr, nullptr, NTOK, 768, 256);
    winattn_k<<<16384, 64, 0, stream>>>(BIG, x, X, rel_table, rel_idx, 0);
  } else {
    for (int b = 0; b < 8; ++b) {
      gemm_mfma<false, false, false><<<dim3(TOKS_PER_B / 64, 3), 256, 0, stream>>>(
          x + (size_t)b * TOKS_PER_B * 256, w_qkv, qkv_b, BIG,
          nullptr, nullptr, nullptr, TOKS_PER_B, 768, 256);
      winattn_k<<<2048, 64, 0, stream>>>(BIG, x, X, rel_table, rel_idx, b);
    }
  }
  // ---- proj ----
  lnstats_k<<<1024, 256, 0, stream>>>(X, stats);
  gemm_mfma<true, true, false><<<dim3(NTOK / 64, 1), 256, 0, stream>>>(
      X, w_proj, proj_b, X, stats, proj_ln_w, proj_ln_b, NTOK, 256, 256);
  // ---- global branch ----
  poolsine_k<<<2048, 256, 0, stream>>>(X, G0);
  gemm_mfma<false, false, false><<<dim3(32, 3), 256, 0, stream>>>(
      G0, w_qkv2, qkv2_b, G1, nullptr, nullptr, nullptr, 2048, 768, 256);
  gattn_k<<<dim3(8, 8), 256, 0, stream>>>(G1, G2);
  upadd_k<<<NTOK, 256, 0, stream>>>(X, G2, stats);
  gemm_mfma<true, true, false><<<dim3(NTOK / 64, 1), 256, 0, stream>>>(
      X, w_proj2, proj2_b, X, stats, proj2_ln_w, proj2_ln_b, NTOK, 256, 256);
  // ---- MLP ----
  lnstats_k<<<1024, 256, 0, stream>>>(X, stats);
  for (int s0 = 0; s0 < NTOK; s0 += st) {
    gemm_mfma<true, false, true><<<dim3(st / 64, 4), 256, 0, stream>>>(
        X + (size_t)s0 * 256, w_fc1, fc1_b, BIG, stats + (size_t)s0 * 2,
        norm1_w, norm1_b, st, 1024, 256);
    gemm_mfma<false, true, false><<<dim3(st / 64, 1), 256, 0, stream>>>(
        BIG, w_fc2, fc2_b, X + (size_t)s0 * 256, nullptr, nullptr, nullptr,
        st, 256, 1024);
  }
  // ---- final LN ----
  finalln_k<<<1024, 256, 0, stream>>>(X, norm2_w, norm2_b);
}